// Round 5
// baseline (447.723 us; speedup 1.0000x reference)
//
#include <hip/hip_runtime.h>

#define IH 1024
#define IW 1024
#define NT 256
#define NBANDS 16        // NT/16
#define PSTR 132         // boundary-plane stride (33 granules, ==1 mod 8 -> class rotation)

__device__ __forceinline__ int refl(int g, int n) {
  return g < 0 ? -g : (g >= n ? 2 * n - 2 - g : g);
}
// granule-parity fix: within a 16-lane band each of the 8 bank-granule classes
// is hit exactly 2x (2-way = free, m136)
__device__ __forceinline__ int pcol(int c) {
  return c ^ (((c >> 5) & 1) << 2);
}
__device__ __forceinline__ float dpp_shr1(float v) {  // lane i <- lane i-1 (16-lane row)
  return __int_as_float(__builtin_amdgcn_update_dpp(
      __float_as_int(v), __float_as_int(v), 0x111, 0xF, 0xF, false));
}
__device__ __forceinline__ float dpp_shl1(float v) {  // lane i <- lane i+1 (16-lane row)
  return __int_as_float(__builtin_amdgcn_update_dpp(
      __float_as_int(v), __float_as_int(v), 0x101, 0xF, 0xF, false));
}
__device__ __forceinline__ float bfi(unsigned int m, float a, float b) {
  return __uint_as_float((m & __float_as_uint(a)) | (~m & __float_as_uint(b)));
}

// STEPS diffusion steps; 7-row x 8-col thread strip in registers, band
// boundaries through parity-double-buffered LDS planes. HALO >= STEPS+2.
// MXF: mask from separate x pointer (pass 2) instead of loaded state (pass 1).
template<int STEPS, int HALO, int RPT, bool MXF>
__global__ __launch_bounds__(NT, 4)
void inpaintR(const float* __restrict__ in, const float* __restrict__ xm,
              const float* __restrict__ wgt, float* __restrict__ out) {
  // topA[p][b] = top row of band b (south ghost for band b-1); topA[p][NB]=static
  // botA[p][b] = bottom row of band b-1 (north ghost for band b); botA[p][0]=static
  __shared__ float topA[2][NBANDS + 1][PSTR];
  __shared__ float botA[2][NBANDS + 1][PSTR];

  constexpr int ROWS = NBANDS * RPT;           // region height
  constexpr int WX   = 128 - 2 * HALO;         // output window x
  constexpr int WY   = ROWS - 2 * HALO;        // output window y
  constexpr int TPX  = (IW + WX - 1) / WX;
  constexpr int TPY  = (IH + WY - 1) / WY;
  constexpr int TPI  = TPX * TPY;
  constexpr int MW   = (RPT * 8 + 31) / 32;    // mask words

  const int tid = threadIdx.x;
  const int bid = blockIdx.x;
  const int img = bid / TPI;                   // 0..15 (B*C)
  const int t   = bid - img * TPI;
  const int ty  = (t / TPX) * WY;
  const int tx  = (t % TPX) * WX;
  const int ch  = img & 1;

  const float* __restrict__ xin = in + (size_t)img * (IH * IW);

  const float wN = wgt[ch * 9 + 1];
  const float wW = wgt[ch * 9 + 3];
  const float wC = wgt[ch * 9 + 4];
  const float wE = wgt[ch * 9 + 5];
  const float wS = wgt[ch * 9 + 7];

  const int xg   = tid & 15;
  const int band = tid >> 4;                   // 0..15
  const int r0   = band * RPT;
  const int c0   = xg * 8;
  const int gr0  = ty - HALO;
  const int gc0  = tx - HALO;

  auto load8 = [&](const float* __restrict__ p, int rr, float v[8]) {
    const float* rp = p + (size_t)refl(gr0 + rr, IH) * IW;
    const int gc = gc0 + c0;
    if (gc >= 0 && gc + 7 < IW) {
      const float4 a = *(const float4*)(rp + gc);
      const float4 b = *(const float4*)(rp + gc + 4);
      v[0]=a.x; v[1]=a.y; v[2]=a.z; v[3]=a.w;
      v[4]=b.x; v[5]=b.y; v[6]=b.z; v[7]=b.w;
    } else {
#pragma unroll
      for (int j = 0; j < 8; ++j) v[j] = rp[refl(gc + j, IW)];
    }
  };

  // ---- state strip + 1-bit-per-cell mask into registers ----
  float s[RPT][8];
  unsigned int mkw[MW];
#pragma unroll
  for (int w = 0; w < MW; ++w) mkw[w] = 0u;
#pragma unroll
  for (int i = 0; i < RPT; ++i) {
    load8(xin, r0 + i, s[i]);
    float mv[8];
    if (MXF) {
      load8(xm + (size_t)img * (IH * IW), r0 + i, mv);
    } else {
#pragma unroll
      for (int j = 0; j < 8; ++j) mv[j] = s[i][j];
    }
    unsigned int byte = 0u;
#pragma unroll
    for (int j = 0; j < 8; ++j) byte |= (mv[j] == 0.0f) ? (1u << j) : 0u;
    mkw[i >> 2] |= byte << ((i & 3) * 8);
  }

  // ---- static ghost columns (only xg 0/15 read them; cone-safe, HALO>=STEPS+2)
  float gle[RPT], gre[RPT];
#pragma unroll
  for (int i = 0; i < RPT; ++i) { gle[i] = 0.0f; gre[i] = 0.0f; }
  if (xg == 0) {
    const int gc = refl(gc0 - 1, IW);
#pragma unroll
    for (int i = 0; i < RPT; ++i)
      gle[i] = xin[(size_t)refl(gr0 + r0 + i, IH) * IW + gc];
  }
  if (xg == 15) {
    const int gc = refl(gc0 + 128, IW);
#pragma unroll
    for (int i = 0; i < RPT; ++i)
      gre[i] = xin[(size_t)refl(gr0 + r0 + i, IH) * IW + gc];
  }

  // ---- static ghost rows (both parities) + initial boundary planes ----
  if (band == 0) {
    float v[8]; load8(xin, -1, v);
    const float4 a = {v[0],v[1],v[2],v[3]};
    const float4 b = {v[4],v[5],v[6],v[7]};
#pragma unroll
    for (int h = 0; h < 2; ++h) {
      *(float4*)&botA[h][0][pcol(c0)]     = a;
      *(float4*)&botA[h][0][pcol(c0 + 4)] = b;
    }
  }
  if (band == NBANDS - 1) {
    float v[8]; load8(xin, ROWS, v);
    const float4 a = {v[0],v[1],v[2],v[3]};
    const float4 b = {v[4],v[5],v[6],v[7]};
#pragma unroll
    for (int h = 0; h < 2; ++h) {
      *(float4*)&topA[h][NBANDS][pcol(c0)]     = a;
      *(float4*)&topA[h][NBANDS][pcol(c0 + 4)] = b;
    }
  }
  {
    const float4 t0 = {s[0][0], s[0][1], s[0][2], s[0][3]};
    const float4 t1 = {s[0][4], s[0][5], s[0][6], s[0][7]};
    *(float4*)&topA[0][band][pcol(c0)]     = t0;
    *(float4*)&topA[0][band][pcol(c0 + 4)] = t1;
    const float4 b0 = {s[RPT-1][0], s[RPT-1][1], s[RPT-1][2], s[RPT-1][3]};
    const float4 b1 = {s[RPT-1][4], s[RPT-1][5], s[RPT-1][6], s[RPT-1][7]};
    *(float4*)&botA[0][band + 1][pcol(c0)]     = b0;
    *(float4*)&botA[0][band + 1][pcol(c0 + 4)] = b1;
  }
  __syncthreads();

  // ---- time loop: all state in registers ----
  int par = 0;
#pragma unroll 1
  for (int st = 0; st < STEPS; ++st) {
    float prev[8], sb[8];
    {
      const float4 a = *(const float4*)&botA[par][band][pcol(c0)];
      const float4 b = *(const float4*)&botA[par][band][pcol(c0 + 4)];
      prev[0]=a.x; prev[1]=a.y; prev[2]=a.z; prev[3]=a.w;
      prev[4]=b.x; prev[5]=b.y; prev[6]=b.z; prev[7]=b.w;
      const float4 c = *(const float4*)&topA[par][band + 1][pcol(c0)];
      const float4 d = *(const float4*)&topA[par][band + 1][pcol(c0 + 4)];
      sb[0]=c.x; sb[1]=c.y; sb[2]=c.z; sb[3]=c.w;
      sb[4]=d.x; sb[5]=d.y; sb[6]=d.z; sb[7]=d.w;
    }
#pragma unroll
    for (int i = 0; i < RPT; ++i) {
      float cur[8];
#pragma unroll
      for (int j = 0; j < 8; ++j) cur[j] = s[i][j];
      float L = dpp_shr1(cur[7]);
      float R = dpp_shl1(cur[0]);
      if (xg == 0)  L = gle[i];
      if (xg == 15) R = gre[i];
#pragma unroll
      for (int j = 0; j < 8; ++j) {
        const float sth = (i < RPT - 1) ? s[i + 1][j] : sb[j];   // old south
        const float l  = j       ? cur[j - 1] : L;
        const float r_ = (j < 7) ? cur[j + 1] : R;
        const float cv = fmaf(wC, cur[j],
                         fmaf(wW, l,
                         fmaf(wE, r_,
                         fmaf(wN, prev[j], wS * sth))));
        const int pos = (i & 3) * 8 + j;
        const unsigned int mm =
            (unsigned int)(((int)(mkw[i >> 2] << (31 - pos))) >> 31);
        s[i][j] = bfi(mm, cv, cur[j]);         // exact: conv if hole else frozen
      }
#pragma unroll
      for (int j = 0; j < 8; ++j) prev[j] = cur[j];
    }
    // publish new boundary rows for neighbor bands (other parity)
    {
      const float4 t0 = {s[0][0], s[0][1], s[0][2], s[0][3]};
      const float4 t1 = {s[0][4], s[0][5], s[0][6], s[0][7]};
      *(float4*)&topA[par ^ 1][band][pcol(c0)]     = t0;
      *(float4*)&topA[par ^ 1][band][pcol(c0 + 4)] = t1;
      const float4 b0 = {s[RPT-1][0], s[RPT-1][1], s[RPT-1][2], s[RPT-1][3]};
      const float4 b1 = {s[RPT-1][4], s[RPT-1][5], s[RPT-1][6], s[RPT-1][7]};
      *(float4*)&botA[par ^ 1][band + 1][pcol(c0)]     = b0;
      *(float4*)&botA[par ^ 1][band + 1][pcol(c0 + 4)] = b1;
    }
    __syncthreads();
    par ^= 1;
  }

  // ---- store own cells inside the output window ----
  float* __restrict__ op = out + (size_t)img * (IH * IW);
#pragma unroll
  for (int i = 0; i < RPT; ++i) {
    const int rr = r0 + i;
    const int gr = gr0 + rr;
    if (rr >= HALO && rr < HALO + WY && gr < IH) {
      if constexpr ((HALO & 3) == 0) {         // granule-aligned window: float4
#pragma unroll
        for (int g = 0; g < 2; ++g) {
          const int cc = c0 + g * 4;
          const int gc = gc0 + cc;
          if (cc >= HALO && cc + 3 < HALO + WX && gc + 3 < IW) {
            const float4 v = {s[i][g*4], s[i][g*4+1], s[i][g*4+2], s[i][g*4+3]};
            *(float4*)&op[(size_t)gr * IW + gc] = v;
          }
        }
      } else {
#pragma unroll
        for (int j = 0; j < 8; ++j) {
          const int cc = c0 + j;
          const int gc = gc0 + cc;
          if (cc >= HALO && cc < HALO + WX && gc < IW)
            op[(size_t)gr * IW + gc] = s[i][j];
        }
      }
    }
  }
}

extern "C" void kernel_launch(void* const* d_in, const int* in_sizes, int n_in,
                              void* d_out, int out_size, void* d_ws, size_t ws_size,
                              hipStream_t stream) {
  (void)in_sizes; (void)n_in; (void)out_size;
  const float* x   = (const float*)d_in[0];
  const float* wgt = (const float*)d_in[1];
  float* out       = (float*)d_out;
  const size_t need = (size_t)16 * IH * IW * sizeof(float);
  if (ws_size >= need) {
    float* ws = (float*)d_ws;
    // 10+10 steps, halo 12: window 104x88, tiles 10x12, 16 imgs -> 1920 blocks
    // (1920 = 1.875 x 1024 resident -> 94% round utilization)
    inpaintR<10, 12, 7, false><<<dim3(1920), dim3(NT), 0, stream>>>(x, x, wgt, ws);
    inpaintR<10, 12, 7, true ><<<dim3(1920), dim3(NT), 0, stream>>>(ws, x, wgt, out);
  } else {
    // fallback: single 20-step pass, halo 22: window 84x68, tiles 13x16
    inpaintR<20, 22, 7, false><<<dim3(16 * 13 * 16), dim3(NT), 0, stream>>>(x, x, wgt, out);
  }
}

// Round 6
// 202.351 us; speedup vs baseline: 2.2126x; 2.2126x over previous
//
#include <hip/hip_runtime.h>

#define IH 1024
#define IW 1024
#define NT 256
#define NBANDS 16        // NT/16
#define PSTR 132         // boundary-plane stride (33 granules, ==1 mod 8 -> class rotation)

__device__ __forceinline__ int refl(int g, int n) {
  return g < 0 ? -g : (g >= n ? 2 * n - 2 - g : g);
}
// granule-parity fix: within a 16-lane band each of the 8 bank-granule classes
// is hit exactly 2x (2-way = free, m136)
__device__ __forceinline__ int pcol(int c) {
  return c ^ (((c >> 5) & 1) << 2);
}
__device__ __forceinline__ float dpp_shr1(float v) {  // lane i <- lane i-1 (16-lane row)
  return __int_as_float(__builtin_amdgcn_update_dpp(
      __float_as_int(v), __float_as_int(v), 0x111, 0xF, 0xF, false));
}
__device__ __forceinline__ float dpp_shl1(float v) {  // lane i <- lane i+1 (16-lane row)
  return __int_as_float(__builtin_amdgcn_update_dpp(
      __float_as_int(v), __float_as_int(v), 0x101, 0xF, 0xF, false));
}
__device__ __forceinline__ float bfi(unsigned int m, float a, float b) {
  return __uint_as_float((m & __float_as_uint(a)) | (~m & __float_as_uint(b)));
}

// STEPS diffusion steps; RPT-row x 8-col thread strip in registers, band
// boundaries through parity-double-buffered LDS planes. HALO >= STEPS+2.
// MXF: mask from separate x pointer (pass 2) instead of loaded state (pass 1).
template<int STEPS, int HALO, int RPT, bool MXF>
__global__ __launch_bounds__(NT, 2)   // min 2 waves/EU -> VGPR cap >=128 (R5: arg 4 capped at 64 -> spilled)
void inpaintR(const float* __restrict__ in, const float* __restrict__ xm,
              const float* __restrict__ wgt, float* __restrict__ out) {
  // topA[p][b] = top row of band b (south ghost for band b-1); topA[p][NB]=static
  // botA[p][b] = bottom row of band b-1 (north ghost for band b); botA[p][0]=static
  __shared__ float topA[2][NBANDS + 1][PSTR];
  __shared__ float botA[2][NBANDS + 1][PSTR];
  __shared__ float gcolL[NBANDS * RPT];   // static ghost cols (col -1 / col 128)
  __shared__ float gcolR[NBANDS * RPT];

  constexpr int ROWS = NBANDS * RPT;           // region height (112)
  static_assert(ROWS <= 128, "ghost-col fill assumes ROWS<=128");
  constexpr int WX   = 128 - 2 * HALO;         // output window x
  constexpr int WY   = ROWS - 2 * HALO;        // output window y
  constexpr int TPX  = (IW + WX - 1) / WX;
  constexpr int TPY  = (IH + WY - 1) / WY;
  constexpr int TPI  = TPX * TPY;
  constexpr int MW   = (RPT * 8 + 31) / 32;    // mask words

  const int tid = threadIdx.x;
  const int bid = blockIdx.x;
  const int img = bid / TPI;                   // 0..15 (B*C)
  const int t   = bid - img * TPI;
  const int ty  = (t / TPX) * WY;
  const int tx  = (t % TPX) * WX;
  const int ch  = img & 1;

  const float* __restrict__ xin = in + (size_t)img * (IH * IW);

  const float wN = wgt[ch * 9 + 1];
  const float wW = wgt[ch * 9 + 3];
  const float wC = wgt[ch * 9 + 4];
  const float wE = wgt[ch * 9 + 5];
  const float wS = wgt[ch * 9 + 7];

  const int xg   = tid & 15;
  const int band = tid >> 4;                   // 0..15
  const int r0   = band * RPT;
  const int c0   = xg * 8;
  const int gr0  = ty - HALO;
  const int gc0  = tx - HALO;

  auto load8 = [&](const float* __restrict__ p, int rr, float v[8]) {
    const float* rp = p + (size_t)refl(gr0 + rr, IH) * IW;
    const int gc = gc0 + c0;
    if (gc >= 0 && gc + 7 < IW) {
      const float4 a = *(const float4*)(rp + gc);
      const float4 b = *(const float4*)(rp + gc + 4);
      v[0]=a.x; v[1]=a.y; v[2]=a.z; v[3]=a.w;
      v[4]=b.x; v[5]=b.y; v[6]=b.z; v[7]=b.w;
    } else {
#pragma unroll
      for (int j = 0; j < 8; ++j) v[j] = rp[refl(gc + j, IW)];
    }
  };

  // ---- static ghost columns into LDS (read by xg 0/15 lanes each step) ----
  if (tid < ROWS)
    gcolL[tid] = xin[(size_t)refl(gr0 + tid, IH) * IW + refl(gc0 - 1, IW)];
  if (tid >= 128 && tid < 128 + ROWS)
    gcolR[tid - 128] = xin[(size_t)refl(gr0 + tid - 128, IH) * IW + refl(gc0 + 128, IW)];

  // ---- state strip + 1-bit-per-cell mask into registers ----
  float s[RPT][8];
  unsigned int mkw[MW];
#pragma unroll
  for (int w = 0; w < MW; ++w) mkw[w] = 0u;
#pragma unroll
  for (int i = 0; i < RPT; ++i) {
    load8(xin, r0 + i, s[i]);
    float mv[8];
    if (MXF) {
      load8(xm + (size_t)img * (IH * IW), r0 + i, mv);
    } else {
#pragma unroll
      for (int j = 0; j < 8; ++j) mv[j] = s[i][j];
    }
    unsigned int byte = 0u;
#pragma unroll
    for (int j = 0; j < 8; ++j) byte |= (mv[j] == 0.0f) ? (1u << j) : 0u;
    mkw[i >> 2] |= byte << ((i & 3) * 8);
  }

  // ---- static ghost rows (both parities) + initial boundary planes ----
  if (band == 0) {
    float v[8]; load8(xin, -1, v);
    const float4 a = {v[0],v[1],v[2],v[3]};
    const float4 b = {v[4],v[5],v[6],v[7]};
#pragma unroll
    for (int h = 0; h < 2; ++h) {
      *(float4*)&botA[h][0][pcol(c0)]     = a;
      *(float4*)&botA[h][0][pcol(c0 + 4)] = b;
    }
  }
  if (band == NBANDS - 1) {
    float v[8]; load8(xin, ROWS, v);
    const float4 a = {v[0],v[1],v[2],v[3]};
    const float4 b = {v[4],v[5],v[6],v[7]};
#pragma unroll
    for (int h = 0; h < 2; ++h) {
      *(float4*)&topA[h][NBANDS][pcol(c0)]     = a;
      *(float4*)&topA[h][NBANDS][pcol(c0 + 4)] = b;
    }
  }
  {
    const float4 t0 = {s[0][0], s[0][1], s[0][2], s[0][3]};
    const float4 t1 = {s[0][4], s[0][5], s[0][6], s[0][7]};
    *(float4*)&topA[0][band][pcol(c0)]     = t0;
    *(float4*)&topA[0][band][pcol(c0 + 4)] = t1;
    const float4 b0 = {s[RPT-1][0], s[RPT-1][1], s[RPT-1][2], s[RPT-1][3]};
    const float4 b1 = {s[RPT-1][4], s[RPT-1][5], s[RPT-1][6], s[RPT-1][7]};
    *(float4*)&botA[0][band + 1][pcol(c0)]     = b0;
    *(float4*)&botA[0][band + 1][pcol(c0 + 4)] = b1;
  }
  __syncthreads();

  // ---- time loop: all state in registers ----
  int par = 0;
#pragma unroll 1
  for (int st = 0; st < STEPS; ++st) {
    float prev[8], sb[8];
    {
      const float4 a = *(const float4*)&botA[par][band][pcol(c0)];
      const float4 b = *(const float4*)&botA[par][band][pcol(c0 + 4)];
      prev[0]=a.x; prev[1]=a.y; prev[2]=a.z; prev[3]=a.w;
      prev[4]=b.x; prev[5]=b.y; prev[6]=b.z; prev[7]=b.w;
      const float4 c = *(const float4*)&topA[par][band + 1][pcol(c0)];
      const float4 d = *(const float4*)&topA[par][band + 1][pcol(c0 + 4)];
      sb[0]=c.x; sb[1]=c.y; sb[2]=c.z; sb[3]=c.w;
      sb[4]=d.x; sb[5]=d.y; sb[6]=d.z; sb[7]=d.w;
    }
#pragma unroll
    for (int i = 0; i < RPT; ++i) {
      float cur[8];
#pragma unroll
      for (int j = 0; j < 8; ++j) cur[j] = s[i][j];
      float L = dpp_shr1(cur[7]);
      float R = dpp_shl1(cur[0]);
      if (xg == 0)  L = gcolL[r0 + i];         // static ghost col (cone-safe)
      if (xg == 15) R = gcolR[r0 + i];
#pragma unroll
      for (int j = 0; j < 8; ++j) {
        const float sth = (i < RPT - 1) ? s[i + 1][j] : sb[j];   // old south
        const float l  = j       ? cur[j - 1] : L;
        const float r_ = (j < 7) ? cur[j + 1] : R;
        const float cv = fmaf(wC, cur[j],
                         fmaf(wW, l,
                         fmaf(wE, r_,
                         fmaf(wN, prev[j], wS * sth))));
        const int pos = (i & 3) * 8 + j;
        const unsigned int mm =
            (unsigned int)(((int)(mkw[i >> 2] << (31 - pos))) >> 31);
        s[i][j] = bfi(mm, cv, cur[j]);         // exact: conv if hole else frozen
      }
#pragma unroll
      for (int j = 0; j < 8; ++j) prev[j] = cur[j];
    }
    // publish new boundary rows for neighbor bands (other parity)
    {
      const float4 t0 = {s[0][0], s[0][1], s[0][2], s[0][3]};
      const float4 t1 = {s[0][4], s[0][5], s[0][6], s[0][7]};
      *(float4*)&topA[par ^ 1][band][pcol(c0)]     = t0;
      *(float4*)&topA[par ^ 1][band][pcol(c0 + 4)] = t1;
      const float4 b0 = {s[RPT-1][0], s[RPT-1][1], s[RPT-1][2], s[RPT-1][3]};
      const float4 b1 = {s[RPT-1][4], s[RPT-1][5], s[RPT-1][6], s[RPT-1][7]};
      *(float4*)&botA[par ^ 1][band + 1][pcol(c0)]     = b0;
      *(float4*)&botA[par ^ 1][band + 1][pcol(c0 + 4)] = b1;
    }
    __syncthreads();
    par ^= 1;
  }

  // ---- store own cells inside the output window ----
  float* __restrict__ op = out + (size_t)img * (IH * IW);
#pragma unroll
  for (int i = 0; i < RPT; ++i) {
    const int rr = r0 + i;
    const int gr = gr0 + rr;
    if (rr >= HALO && rr < HALO + WY && gr < IH) {
      if constexpr ((HALO & 3) == 0) {         // granule-aligned window: float4
#pragma unroll
        for (int g = 0; g < 2; ++g) {
          const int cc = c0 + g * 4;
          const int gc = gc0 + cc;
          if (cc >= HALO && cc + 3 < HALO + WX && gc + 3 < IW) {
            const float4 v = {s[i][g*4], s[i][g*4+1], s[i][g*4+2], s[i][g*4+3]};
            *(float4*)&op[(size_t)gr * IW + gc] = v;
          }
        }
      } else {
#pragma unroll
        for (int j = 0; j < 8; ++j) {
          const int cc = c0 + j;
          const int gc = gc0 + cc;
          if (cc >= HALO && cc < HALO + WX && gc < IW)
            op[(size_t)gr * IW + gc] = s[i][j];
        }
      }
    }
  }
}

extern "C" void kernel_launch(void* const* d_in, const int* in_sizes, int n_in,
                              void* d_out, int out_size, void* d_ws, size_t ws_size,
                              hipStream_t stream) {
  (void)in_sizes; (void)n_in; (void)out_size;
  const float* x   = (const float*)d_in[0];
  const float* wgt = (const float*)d_in[1];
  float* out       = (float*)d_out;
  const size_t need = (size_t)16 * IH * IW * sizeof(float);
  if (ws_size >= need) {
    float* ws = (float*)d_ws;
    // 10+10 steps, halo 12: window 104x88, tiles 10x12, 16 imgs -> 1920 blocks
    // (4 blocks/CU -> 1024 resident -> 93.75% round utilization)
    inpaintR<10, 12, 7, false><<<dim3(1920), dim3(NT), 0, stream>>>(x, x, wgt, ws);
    inpaintR<10, 12, 7, true ><<<dim3(1920), dim3(NT), 0, stream>>>(ws, x, wgt, out);
  } else {
    // fallback: single 20-step pass, halo 22: window 84x68, tiles 13x16
    inpaintR<20, 22, 7, false><<<dim3(16 * 13 * 16), dim3(NT), 0, stream>>>(x, x, wgt, out);
  }
}

// Round 7
// 171.162 us; speedup vs baseline: 2.6158x; 1.1822x over previous
//
#include <hip/hip_runtime.h>

#define IH 1024
#define IW 1024
#define NT 256
#define NBANDS 16        // NT/16
#define PSTR 132         // boundary-plane stride (33 granules, ==1 mod 8 -> class rotation)

__device__ __forceinline__ int refl(int g, int n) {
  return g < 0 ? -g : (g >= n ? 2 * n - 2 - g : g);
}
// granule-parity fix: within a 16-lane band each of the 8 bank-granule classes
// is hit exactly 2x (2-way = free, m136)
__device__ __forceinline__ int pcol(int c) {
  return c ^ (((c >> 5) & 1) << 2);
}
__device__ __forceinline__ float dpp_shr1(float v) {  // lane i <- lane i-1 (16-lane row)
  return __int_as_float(__builtin_amdgcn_update_dpp(
      __float_as_int(v), __float_as_int(v), 0x111, 0xF, 0xF, false));
}
__device__ __forceinline__ float dpp_shl1(float v) {  // lane i <- lane i+1 (16-lane row)
  return __int_as_float(__builtin_amdgcn_update_dpp(
      __float_as_int(v), __float_as_int(v), 0x101, 0xF, 0xF, false));
}
__device__ __forceinline__ float bfi(unsigned int m, float a, float b) {
  return __uint_as_float((m & __float_as_uint(a)) | (~m & __float_as_uint(b)));
}

// STEPS diffusion steps; RPT-row x 8-col thread strip in registers, band
// boundaries through parity-double-buffered LDS planes.
// Frozen ring: outermost region cells get mask=known -> they hold their
// initial value = static ghosts, no special edge handling anywhere.
// Cone: cell at L1 distance d from ring is exact through step d; window
// offset YOFF/XOFF >= STEPS+2 > STEPS guarantees exactness (proven V(k)=k).
// MXF: mask from separate x pointer (pass 2) instead of loaded state (pass 1).
template<int STEPS, int RPT, int YOFF, int WY, int XOFF, int WX, bool MXF>
__global__ __launch_bounds__(NT, 2)   // R5 lesson: tighter bound spilled (VGPR 64); (NT,2) -> 96-112, no spill
void inpaintR(const float* __restrict__ in, const float* __restrict__ xm,
              const float* __restrict__ wgt, float* __restrict__ out) {
  // topA[p][b] = top row (s[0]) of band b, read by band b-1 as south plane
  // botA[p][b] = bottom row (s[RPT-1]) of band b-1, read by band b as north plane
  __shared__ float topA[2][NBANDS + 1][PSTR];
  __shared__ float botA[2][NBANDS + 1][PSTR];

  constexpr int ROWS = NBANDS * RPT;           // region height (112)
  constexpr int TPX  = (IW + WX - 1) / WX;
  constexpr int TPY  = (IH + WY - 1) / WY;
  constexpr int TPI  = TPX * TPY;
  constexpr int MW   = (RPT * 8 + 31) / 32;    // mask words
  static_assert((YOFF & 3) == 0 && (XOFF & 3) == 0, "granule-aligned window");
  static_assert(RPT >= 3, "row schedule assumes >=3 rows");

  const int tid = threadIdx.x;
  const int bid = blockIdx.x;
  const int img = bid / TPI;                   // 0..15 (B*C)
  const int t   = bid - img * TPI;
  const int ty  = (t / TPX) * WY;
  const int tx  = (t % TPX) * WX;
  const int ch  = img & 1;

  const float* __restrict__ xin = in + (size_t)img * (IH * IW);

  const float wN = wgt[ch * 9 + 1];
  const float wW = wgt[ch * 9 + 3];
  const float wC = wgt[ch * 9 + 4];
  const float wE = wgt[ch * 9 + 5];
  const float wS = wgt[ch * 9 + 7];

  const int xg   = tid & 15;
  const int band = tid >> 4;                   // 0..15
  const int r0   = band * RPT;
  const int c0   = xg * 8;
  const int gr0  = ty - YOFF;
  const int gc0  = tx - XOFF;

  auto load8 = [&](const float* __restrict__ p, int rr, float v[8]) {
    const float* rp = p + (size_t)refl(gr0 + rr, IH) * IW;
    const int gc = gc0 + c0;
    if (gc >= 0 && gc + 7 < IW) {
      const float4 a = *(const float4*)(rp + gc);
      const float4 b = *(const float4*)(rp + gc + 4);
      v[0]=a.x; v[1]=a.y; v[2]=a.z; v[3]=a.w;
      v[4]=b.x; v[5]=b.y; v[6]=b.z; v[7]=b.w;
    } else {
#pragma unroll
      for (int j = 0; j < 8; ++j) v[j] = rp[refl(gc + j, IW)];
    }
  };

  // ---- state strip + 1-bit-per-cell mask into registers ----
  float s[RPT][8];
  unsigned int mkw[MW];
#pragma unroll
  for (int w = 0; w < MW; ++w) mkw[w] = 0u;
#pragma unroll
  for (int i = 0; i < RPT; ++i) {
    load8(xin, r0 + i, s[i]);
    float mv[8];
    if (MXF) {
      load8(xm + (size_t)img * (IH * IW), r0 + i, mv);
    } else {
#pragma unroll
      for (int j = 0; j < 8; ++j) mv[j] = s[i][j];
    }
    unsigned int byte = 0u;
#pragma unroll
    for (int j = 0; j < 8; ++j) byte |= (mv[j] == 0.0f) ? (1u << j) : 0u;
    mkw[i >> 2] |= byte << ((i & 3) * 8);
  }

  // ---- frozen ring: force outermost region cells to "known" ----
  if (band == 0)          mkw[0] &= ~0xFFu;                                  // region row 0
  if (band == NBANDS - 1) mkw[(RPT-1) >> 2] &= ~(0xFFu << (((RPT-1) & 3) * 8)); // row ROWS-1
  if (xg == 0) {
#pragma unroll
    for (int i = 0; i < RPT; ++i) mkw[i >> 2] &= ~(0x01u << ((i & 3) * 8));  // col 0
  }
  if (xg == 15) {
#pragma unroll
    for (int i = 0; i < RPT; ++i) mkw[i >> 2] &= ~(0x80u << ((i & 3) * 8));  // col 127
  }

  // ---- initial boundary planes (parity 0) + zero the never-written edges ----
  {
    const float4 t0 = {s[0][0], s[0][1], s[0][2], s[0][3]};
    const float4 t1 = {s[0][4], s[0][5], s[0][6], s[0][7]};
    *(float4*)&topA[0][band][pcol(c0)]     = t0;
    *(float4*)&topA[0][band][pcol(c0 + 4)] = t1;
    const float4 b0 = {s[RPT-1][0], s[RPT-1][1], s[RPT-1][2], s[RPT-1][3]};
    const float4 b1 = {s[RPT-1][4], s[RPT-1][5], s[RPT-1][6], s[RPT-1][7]};
    *(float4*)&botA[0][band + 1][pcol(c0)]     = b0;
    *(float4*)&botA[0][band + 1][pcol(c0 + 4)] = b1;
    const float4 z = {0.f, 0.f, 0.f, 0.f};
    if (band == 0) {                           // planes read by frozen rows (values masked away)
#pragma unroll
      for (int h = 0; h < 2; ++h) {
        *(float4*)&botA[h][0][pcol(c0)]     = z;
        *(float4*)&botA[h][0][pcol(c0 + 4)] = z;
      }
    }
    if (band == NBANDS - 1) {
#pragma unroll
      for (int h = 0; h < 2; ++h) {
        *(float4*)&topA[h][NBANDS][pcol(c0)]     = z;
        *(float4*)&topA[h][NBANDS][pcol(c0 + 4)] = z;
      }
    }
  }
  __syncthreads();

  // one row of the strip: nw = select(mask, conv(north,cur,south), cur)
  auto dorow = [&](int i, const float north[8], const float cur[8],
                   const float south[8], float nw[8]) {
    const float L = dpp_shr1(cur[7]);          // edge-lane garbage masked by frozen ring
    const float R = dpp_shl1(cur[0]);
#pragma unroll
    for (int j = 0; j < 8; ++j) {
      const float l  = j       ? cur[j - 1] : L;
      const float r_ = (j < 7) ? cur[j + 1] : R;
      const float cv = fmaf(wC, cur[j],
                       fmaf(wW, l,
                       fmaf(wE, r_,
                       fmaf(wN, north[j], wS * south[j]))));
      const unsigned int mm =
          (unsigned int)(((int)(mkw[i >> 2] << (31 - ((i & 3) * 8 + j)))) >> 31);
      nw[j] = bfi(mm, cv, cur[j]);             // exact: conv if hole else frozen
    }
  };

  // ---- time loop: all state in registers; middle rows first so the plane
  //      reads (nb/sb) issued at the top are consumed ~5 rows later ----
  int par = 0;
#pragma unroll 1
  for (int st = 0; st < STEPS; ++st) {
    float nb[8], sb[8];
    {
      const float4 a = *(const float4*)&botA[par][band][pcol(c0)];
      const float4 b = *(const float4*)&botA[par][band][pcol(c0 + 4)];
      nb[0]=a.x; nb[1]=a.y; nb[2]=a.z; nb[3]=a.w;
      nb[4]=b.x; nb[5]=b.y; nb[6]=b.z; nb[7]=b.w;
      const float4 c = *(const float4*)&topA[par][band + 1][pcol(c0)];
      const float4 d = *(const float4*)&topA[par][band + 1][pcol(c0 + 4)];
      sb[0]=c.x; sb[1]=c.y; sb[2]=c.z; sb[3]=c.w;
      sb[4]=d.x; sb[5]=d.y; sb[6]=d.z; sb[7]=d.w;
    }
    float north[8], oldS1[8], nw[8];
#pragma unroll
    for (int j = 0; j < 8; ++j) { north[j] = s[0][j]; oldS1[j] = s[1][j]; }
#pragma unroll
    for (int i = 1; i < RPT - 1; ++i) {        // middle rows: registers only
      dorow(i, north, s[i], s[i + 1], nw);
#pragma unroll
      for (int j = 0; j < 8; ++j) { north[j] = s[i][j]; s[i][j] = nw[j]; }
    }
    dorow(RPT - 1, north, s[RPT - 1], sb, nw); // first use of sb
#pragma unroll
    for (int j = 0; j < 8; ++j) s[RPT - 1][j] = nw[j];
    dorow(0, nb, s[0], oldS1, nw);             // first use of nb (last)
#pragma unroll
    for (int j = 0; j < 8; ++j) s[0][j] = nw[j];
    // publish boundary rows for neighbor bands (other parity)
    {
      const float4 t0 = {s[0][0], s[0][1], s[0][2], s[0][3]};
      const float4 t1 = {s[0][4], s[0][5], s[0][6], s[0][7]};
      *(float4*)&topA[par ^ 1][band][pcol(c0)]     = t0;
      *(float4*)&topA[par ^ 1][band][pcol(c0 + 4)] = t1;
      const float4 b0 = {s[RPT-1][0], s[RPT-1][1], s[RPT-1][2], s[RPT-1][3]};
      const float4 b1 = {s[RPT-1][4], s[RPT-1][5], s[RPT-1][6], s[RPT-1][7]};
      *(float4*)&botA[par ^ 1][band + 1][pcol(c0)]     = b0;
      *(float4*)&botA[par ^ 1][band + 1][pcol(c0 + 4)] = b1;
    }
    __syncthreads();
    par ^= 1;
  }

  // ---- store own cells inside the (granule-aligned) output window ----
  float* __restrict__ op = out + (size_t)img * (IH * IW);
#pragma unroll
  for (int i = 0; i < RPT; ++i) {
    const int rr = r0 + i;
    const int gr = gr0 + rr;
    if (rr >= YOFF && rr < YOFF + WY && gr < IH) {
#pragma unroll
      for (int g = 0; g < 2; ++g) {
        const int cc = c0 + g * 4;
        const int gc = gc0 + cc;
        if (cc >= XOFF && cc + 3 < XOFF + WX && gc + 3 < IW) {
          const float4 v = {s[i][g*4], s[i][g*4+1], s[i][g*4+2], s[i][g*4+3]};
          *(float4*)&op[(size_t)gr * IW + gc] = v;
        }
      }
    }
  }
}

extern "C" void kernel_launch(void* const* d_in, const int* in_sizes, int n_in,
                              void* d_out, int out_size, void* d_ws, size_t ws_size,
                              hipStream_t stream) {
  (void)in_sizes; (void)n_in; (void)out_size;
  const float* x   = (const float*)d_in[0];
  const float* wgt = (const float*)d_in[1];
  float* out       = (float*)d_out;
  const size_t need = (size_t)16 * IH * IW * sizeof(float);
  if (ws_size >= need) {
    float* ws = (float*)d_ws;
    // 10+10 steps; window 104x90 at offset (12,12): tiles 10x12, 16 imgs -> 1920
    inpaintR<10, 7, 12, 90, 12, 104, false><<<dim3(1920), dim3(NT), 0, stream>>>(x, x, wgt, ws);
    inpaintR<10, 7, 12, 90, 12, 104, true ><<<dim3(1920), dim3(NT), 0, stream>>>(ws, x, wgt, out);
  } else {
    // fallback: single 20-step pass; window 88x72 at offset (20,20): 12x15 tiles
    inpaintR<20, 7, 20, 72, 20, 88, false><<<dim3(16 * 12 * 15), dim3(NT), 0, stream>>>(x, x, wgt, out);
  }
}

// Round 8
// 147.306 us; speedup vs baseline: 3.0394x; 1.1620x over previous
//
#include <hip/hip_runtime.h>

#define IH 1024
#define IW 1024
#define NT 256
#define NBANDS 16        // NT/16
#define PSTR 132         // boundary-plane stride (33 granules, ==1 mod 8 -> class rotation)

__device__ __forceinline__ int refl(int g, int n) {
  return g < 0 ? -g : (g >= n ? 2 * n - 2 - g : g);
}
// granule-parity fix: within a 16-lane band each of the 8 bank-granule classes
// is hit exactly 2x (2-way = free, m136)
__device__ __forceinline__ int pcol(int c) {
  return c ^ (((c >> 5) & 1) << 2);
}
__device__ __forceinline__ float dpp_shr1(float v) {  // lane i <- lane i-1 (16-lane row)
  return __int_as_float(__builtin_amdgcn_update_dpp(
      __float_as_int(v), __float_as_int(v), 0x111, 0xF, 0xF, false));
}
__device__ __forceinline__ float dpp_shl1(float v) {  // lane i <- lane i+1 (16-lane row)
  return __int_as_float(__builtin_amdgcn_update_dpp(
      __float_as_int(v), __float_as_int(v), 0x101, 0xF, 0xF, false));
}
__device__ __forceinline__ float bfi(unsigned int m, float a, float b) {
  return __uint_as_float((m & __float_as_uint(a)) | (~m & __float_as_uint(b)));
}

// STEPS diffusion steps; RPT-row x 8-col thread strip in registers, band
// boundaries through parity-double-buffered LDS planes.
// Frozen ring: outermost region cells forced to "known" -> hold initial value
// (= static ghosts). Window offset YOFF/XOFF >= STEPS+2 keeps output exact.
// MODE: 0 = standalone (mask from value==0, plain store)
//       1 = pass1   (mask from value==0, store with hole bit in mantissa LSB)
//       2 = pass2   (mask from LSB of loaded values, plain store)
template<int STEPS, int RPT, int YOFF, int WY, int XOFF, int WX, int MODE>
__global__ __launch_bounds__(NT, 2)   // (NT,4) capped VGPR at 64 and spilled (R5); this gives ~88, no spill
void inpaintR(const float* __restrict__ in, const float* __restrict__ wgt,
              float* __restrict__ out) {
  // topA[p][b] = top row (s[0]) of band b, read by band b-1 as south plane
  // botA[p][b] = bottom row (s[RPT-1]) of band b-1, read by band b as north plane
  __shared__ float topA[2][NBANDS + 1][PSTR];
  __shared__ float botA[2][NBANDS + 1][PSTR];

  constexpr int ROWS = NBANDS * RPT;           // region height (112)
  constexpr int TPX  = (IW + WX - 1) / WX;
  constexpr int TPY  = (IH + WY - 1) / WY;
  constexpr int TPI  = TPX * TPY;
  constexpr int MW   = (RPT * 8 + 31) / 32;    // mask words
  static_assert((YOFF & 3) == 0 && (XOFF & 3) == 0, "granule-aligned window");
  static_assert(RPT >= 3 && (STEPS % 2) == 0, "schedule assumptions");

  const int tid = threadIdx.x;
  const int bid = blockIdx.x;
  const int img = bid / TPI;                   // 0..15 (B*C)
  const int t   = bid - img * TPI;
  const int ty  = (t / TPX) * WY;
  const int tx  = (t % TPX) * WX;
  const int ch  = img & 1;

  const float* __restrict__ xin = in + (size_t)img * (IH * IW);

  const float wN = wgt[ch * 9 + 1];
  const float wW = wgt[ch * 9 + 3];
  const float wC = wgt[ch * 9 + 4];
  const float wE = wgt[ch * 9 + 5];
  const float wS = wgt[ch * 9 + 7];

  const int xg   = tid & 15;
  const int band = tid >> 4;                   // 0..15
  const int r0   = band * RPT;
  const int c0   = xg * 8;
  const int gr0  = ty - YOFF;
  const int gc0  = tx - XOFF;
  const int gcc  = gc0 + c0;

  // ---- state strip: interior tiles take the straight-line path ----
  float s[RPT][8];
  const bool interior = (gr0 >= 0) && (gr0 + ROWS <= IH) &&
                        (gc0 >= 0) && (gc0 + 128 <= IW);
  if (interior) {
    const float* rp = xin + (size_t)(gr0 + r0) * IW + gcc;
#pragma unroll
    for (int i = 0; i < RPT; ++i) {
      const float4 a = *(const float4*)(rp);
      const float4 b = *(const float4*)(rp + 4);
      s[i][0]=a.x; s[i][1]=a.y; s[i][2]=a.z; s[i][3]=a.w;
      s[i][4]=b.x; s[i][5]=b.y; s[i][6]=b.z; s[i][7]=b.w;
      rp += IW;
    }
  } else {
#pragma unroll
    for (int i = 0; i < RPT; ++i) {
      const float* rp = xin + (size_t)refl(gr0 + r0 + i, IH) * IW;
      if (gcc >= 0 && gcc + 7 < IW) {
        const float4 a = *(const float4*)(rp + gcc);
        const float4 b = *(const float4*)(rp + gcc + 4);
        s[i][0]=a.x; s[i][1]=a.y; s[i][2]=a.z; s[i][3]=a.w;
        s[i][4]=b.x; s[i][5]=b.y; s[i][6]=b.z; s[i][7]=b.w;
      } else {
#pragma unroll
        for (int j = 0; j < 8; ++j) s[i][j] = rp[refl(gcc + j, IW)];
      }
    }
  }

  // ---- 1-bit-per-cell mask (pass2: from mantissa LSB planted by pass1) ----
  unsigned int mkw[MW];
#pragma unroll
  for (int w = 0; w < MW; ++w) mkw[w] = 0u;
#pragma unroll
  for (int i = 0; i < RPT; ++i) {
    unsigned int byte = 0u;
#pragma unroll
    for (int j = 0; j < 8; ++j) {
      if (MODE == 2) byte |= (__float_as_uint(s[i][j]) & 1u) << j;
      else           byte |= (s[i][j] == 0.0f ? 1u : 0u) << j;
    }
    mkw[i >> 2] |= byte << ((i & 3) * 8);
  }

  // ---- frozen ring: outermost region cells become "known" ----
  if (band == 0)          mkw[0] &= ~0xFFu;
  if (band == NBANDS - 1) mkw[(RPT-1) >> 2] &= ~(0xFFu << (((RPT-1) & 3) * 8));
  if (xg == 0) {
#pragma unroll
    for (int i = 0; i < RPT; ++i) mkw[i >> 2] &= ~(0x01u << ((i & 3) * 8));
  }
  if (xg == 15) {
#pragma unroll
    for (int i = 0; i < RPT; ++i) mkw[i >> 2] &= ~(0x80u << ((i & 3) * 8));
  }

  // ---- initial boundary planes (parity 0) + deterministic edge planes ----
  {
    const float4 t0 = {s[0][0], s[0][1], s[0][2], s[0][3]};
    const float4 t1 = {s[0][4], s[0][5], s[0][6], s[0][7]};
    *(float4*)&topA[0][band][pcol(c0)]     = t0;
    *(float4*)&topA[0][band][pcol(c0 + 4)] = t1;
    const float4 b0 = {s[RPT-1][0], s[RPT-1][1], s[RPT-1][2], s[RPT-1][3]};
    const float4 b1 = {s[RPT-1][4], s[RPT-1][5], s[RPT-1][6], s[RPT-1][7]};
    *(float4*)&botA[0][band + 1][pcol(c0)]     = b0;
    *(float4*)&botA[0][band + 1][pcol(c0 + 4)] = b1;
    const float4 z = {0.f, 0.f, 0.f, 0.f};
    if (band == 0) {                           // read by frozen rows, bitwise-masked away
#pragma unroll
      for (int h = 0; h < 2; ++h) {
        *(float4*)&botA[h][0][pcol(c0)]     = z;
        *(float4*)&botA[h][0][pcol(c0 + 4)] = z;
      }
    }
    if (band == NBANDS - 1) {
#pragma unroll
      for (int h = 0; h < 2; ++h) {
        *(float4*)&topA[h][NBANDS][pcol(c0)]     = z;
        *(float4*)&topA[h][NBANDS][pcol(c0 + 4)] = z;
      }
    }
  }
  __syncthreads();

  // one row: nw = select(mask, conv(north,cur,south), cur)
  auto dorow = [&](int i, const float north[8], const float cur[8],
                   const float south[8], float nw[8]) {
    const float L = dpp_shr1(cur[7]);          // edge-lane garbage masked by frozen ring
    const float R = dpp_shl1(cur[0]);
#pragma unroll
    for (int j = 0; j < 8; ++j) {
      const float l  = j       ? cur[j - 1] : L;
      const float r_ = (j < 7) ? cur[j + 1] : R;
      const float cv = fmaf(wC, cur[j],
                       fmaf(wW, l,
                       fmaf(wE, r_,
                       fmaf(wN, north[j], wS * south[j]))));
      const unsigned int mm =
          (unsigned int)(((int)(mkw[i >> 2] << (31 - ((i & 3) * 8 + j)))) >> 31);
      nw[j] = bfi(mm, cv, cur[j]);             // exact: conv if hole else frozen
    }
  };

  // one step with compile-time plane parity; middle rows first so plane reads
  // (issued at top) are consumed ~RPT rows later
  auto dostep = [&](int par) {
    float nb[8], sb[8];
    {
      const float4 a = *(const float4*)&botA[par][band][pcol(c0)];
      const float4 b = *(const float4*)&botA[par][band][pcol(c0 + 4)];
      nb[0]=a.x; nb[1]=a.y; nb[2]=a.z; nb[3]=a.w;
      nb[4]=b.x; nb[5]=b.y; nb[6]=b.z; nb[7]=b.w;
      const float4 c = *(const float4*)&topA[par][band + 1][pcol(c0)];
      const float4 d = *(const float4*)&topA[par][band + 1][pcol(c0 + 4)];
      sb[0]=c.x; sb[1]=c.y; sb[2]=c.z; sb[3]=c.w;
      sb[4]=d.x; sb[5]=d.y; sb[6]=d.z; sb[7]=d.w;
    }
    float north[8], oldS1[8], nw[8];
#pragma unroll
    for (int j = 0; j < 8; ++j) { north[j] = s[0][j]; oldS1[j] = s[1][j]; }
#pragma unroll
    for (int i = 1; i < RPT - 1; ++i) {        // middle rows: registers only
      dorow(i, north, s[i], s[i + 1], nw);
#pragma unroll
      for (int j = 0; j < 8; ++j) { north[j] = s[i][j]; s[i][j] = nw[j]; }
    }
    dorow(RPT - 1, north, s[RPT - 1], sb, nw); // first use of sb
#pragma unroll
    for (int j = 0; j < 8; ++j) s[RPT - 1][j] = nw[j];
    dorow(0, nb, s[0], oldS1, nw);             // first use of nb (last)
#pragma unroll
    for (int j = 0; j < 8; ++j) s[0][j] = nw[j];
    {
      const float4 t0 = {s[0][0], s[0][1], s[0][2], s[0][3]};
      const float4 t1 = {s[0][4], s[0][5], s[0][6], s[0][7]};
      *(float4*)&topA[par ^ 1][band][pcol(c0)]     = t0;
      *(float4*)&topA[par ^ 1][band][pcol(c0 + 4)] = t1;
      const float4 b0 = {s[RPT-1][0], s[RPT-1][1], s[RPT-1][2], s[RPT-1][3]};
      const float4 b1 = {s[RPT-1][4], s[RPT-1][5], s[RPT-1][6], s[RPT-1][7]};
      *(float4*)&botA[par ^ 1][band + 1][pcol(c0)]     = b0;
      *(float4*)&botA[par ^ 1][band + 1][pcol(c0 + 4)] = b1;
    }
  };

#pragma unroll 1
  for (int it = 0; it < STEPS / 2; ++it) {     // constant parity per call
    dostep(0);
    __syncthreads();
    dostep(1);
    __syncthreads();
  }

  // ---- store own cells inside the (granule-aligned) output window ----
  float* __restrict__ op = out + (size_t)img * (IH * IW);
#pragma unroll
  for (int i = 0; i < RPT; ++i) {
    const int rr = r0 + i;
    const int gr = gr0 + rr;
    if (rr >= YOFF && rr < YOFF + WY && gr < IH) {
#pragma unroll
      for (int g = 0; g < 2; ++g) {
        const int cc = c0 + g * 4;
        const int gc = gc0 + cc;
        if (cc >= XOFF && cc + 3 < XOFF + WX && gc + 3 < IW) {
          float4 v = {s[i][g*4], s[i][g*4+1], s[i][g*4+2], s[i][g*4+3]};
          if (MODE == 1) {                     // plant hole bit in mantissa LSB (<=1 ulp)
            float* e = (float*)&v;
#pragma unroll
            for (int k = 0; k < 4; ++k) {
              const unsigned int hb =
                  (mkw[i >> 2] >> ((i & 3) * 8 + g * 4 + k)) & 1u;
              e[k] = __uint_as_float((__float_as_uint(e[k]) & ~1u) | hb);
            }
          }
          *(float4*)&op[(size_t)gr * IW + gc] = v;
        }
      }
    }
  }
}

extern "C" void kernel_launch(void* const* d_in, const int* in_sizes, int n_in,
                              void* d_out, int out_size, void* d_ws, size_t ws_size,
                              hipStream_t stream) {
  (void)in_sizes; (void)n_in; (void)out_size;
  const float* x   = (const float*)d_in[0];
  const float* wgt = (const float*)d_in[1];
  float* out       = (float*)d_out;
  const size_t need = (size_t)16 * IH * IW * sizeof(float);
  if (ws_size >= need) {
    float* ws = (float*)d_ws;
    // 10+10 steps; window 104x90 at offset (12,12): tiles 10x12, 16 imgs -> 1920
    inpaintR<10, 7, 12, 90, 12, 104, 1><<<dim3(1920), dim3(NT), 0, stream>>>(x, wgt, ws);
    inpaintR<10, 7, 12, 90, 12, 104, 2><<<dim3(1920), dim3(NT), 0, stream>>>(ws, wgt, out);
  } else {
    // fallback: single 20-step pass; window 88x72 at offset (20,20): 12x15 tiles
    inpaintR<20, 7, 20, 72, 20, 88, 0><<<dim3(16 * 12 * 15), dim3(NT), 0, stream>>>(x, wgt, out);
  }
}